// Round 1
// baseline (643.081 us; speedup 1.0000x reference)
//
#include <hip/hip_runtime.h>
#include <hip/hip_bf16.h>

typedef unsigned short u16;
typedef __attribute__((ext_vector_type(8))) short  bf16x8;
typedef __attribute__((ext_vector_type(4))) float  f32x4;
typedef __attribute__((ext_vector_type(4))) int    i32x4;
typedef __attribute__((ext_vector_type(4))) float  f32x4v;

#define MFMA16(a,b,c) __builtin_amdgcn_mfma_f32_16x16x32_bf16((a),(b),(c),0,0,0)

// ---------- constants ----------
// B=4, S=1024, D=1024, H=16, HD=64
// qkv layout: [4096 rows][3072 cols] bf16, cols 0-1023=q, 1024-2047=k, 2048-3071=v
// vt layout:  [b][h][hd(64)][s(1024)] bf16
// mixed:      [b][g][s][t] bf16 (raw mixed_prev, ALPHA applied in attn)

static constexpr size_t OFF_HBF = 0;                 // 4096*1024*2   = 8388608
static constexpr size_t OFF_WBF = 8388608;           // 3072*1024*2   = 6291456
static constexpr size_t OFF_QKV = 14680064;          // 4096*3072*2   = 25165824
static constexpr size_t OFF_VT  = 39845888;          // 4*16*64*1024*2= 8388608
static constexpr size_t OFF_MIX = 48234496;          // 4*16*1024*1024*2 = 134217728

__device__ __forceinline__ u16 f2b(float f) {
  unsigned int u = __builtin_bit_cast(unsigned int, f);
  unsigned int r = (u + 0x7fffu + ((u >> 16) & 1u)) >> 16;
  return (u16)r;
}
__device__ __forceinline__ float b2f(u16 x) {
  union { unsigned int u; float f; } c; c.u = ((unsigned int)x) << 16; return c.f;
}

// ---------------- kernel 1: fp32 -> bf16 convert (hidden + Wq|Wk|Wv) -------------
__global__ void __launch_bounds__(256) k_convert(
    const float* __restrict__ hid, const float* __restrict__ wq,
    const float* __restrict__ wk,  const float* __restrict__ wv,
    u16* __restrict__ hbf, u16* __restrict__ wbf)
{
  int i4 = blockIdx.x * 256 + threadIdx.x;     // 0..1835007, each handles 4 floats
  f32x4v v; u16* dst;
  if (i4 < 1048576) {
    v = *(const f32x4v*)(hid + (size_t)i4 * 4);
    dst = hbf + (size_t)i4 * 4;
  } else {
    int j = (i4 - 1048576) * 4;                // 0..3145727 over [3072][1024]
    const float* s = (j < 1048576) ? (wq + j)
                   : (j < 2097152) ? (wk + (j - 1048576))
                                   : (wv + (j - 2097152));
    v = *(const f32x4v*)s;
    dst = wbf + j;
  }
  u16 o[4];
  for (int k = 0; k < 4; ++k) o[k] = f2b(v[k]);
  *(unsigned long long*)dst = *(unsigned long long*)o;
}

// ---------------- kernel 2: fused QKV GEMM (bf16 MFMA) ---------------------------
// out[m][n] = sum_k hidden[m][k] * W[n][k] + bias[n],  M=4096,N=3072,K=1024
__global__ void __launch_bounds__(256) k_qkv(
    const u16* __restrict__ Abf, const u16* __restrict__ Wbf,
    const float* __restrict__ bq, const float* __restrict__ bk,
    const float* __restrict__ bv, u16* __restrict__ qkv)
{
  __shared__ __align__(16) u16 As[128][32];
  __shared__ __align__(16) u16 Bs[128][32];
  const int n0 = blockIdx.x * 128;
  const int m0 = blockIdx.y * 128;
  const int tid = threadIdx.x;
  const int l = tid & 63, w = tid >> 6;
  const int lr = l & 15, lg = l >> 4;
  const int wm = (w >> 1) * 64, wn = (w & 1) * 64;

  f32x4 acc[4][4] = {};
  i32x4 ra[2], rb[2];

  auto loadT = [&](int k0) {
    for (int i = 0; i < 2; ++i) {
      int c = tid + i * 256;
      int row = c >> 2, col8 = (c & 3) * 8;
      ra[i] = *(const i32x4*)(Abf + (size_t)(m0 + row) * 1024 + k0 + col8);
      rb[i] = *(const i32x4*)(Wbf + (size_t)(n0 + row) * 1024 + k0 + col8);
    }
  };
  loadT(0);
  for (int k0 = 0; k0 < 1024; k0 += 32) {
    __syncthreads();
    for (int i = 0; i < 2; ++i) {
      int c = tid + i * 256;
      int row = c >> 2, col8 = (c & 3) * 8;
      *(i32x4*)(&As[row][col8]) = ra[i];
      *(i32x4*)(&Bs[row][col8]) = rb[i];
    }
    __syncthreads();
    if (k0 + 32 < 1024) loadT(k0 + 32);
    bf16x8 a[4], bb[4];
    for (int mi = 0; mi < 4; ++mi)
      a[mi] = *(const bf16x8*)(&As[wm + mi * 16 + lr][lg * 8]);
    for (int ni = 0; ni < 4; ++ni)
      bb[ni] = *(const bf16x8*)(&Bs[wn + ni * 16 + lr][lg * 8]);
    for (int mi = 0; mi < 4; ++mi)
      for (int ni = 0; ni < 4; ++ni)
        acc[mi][ni] = MFMA16(a[mi], bb[ni], acc[mi][ni]);
  }
  for (int mi = 0; mi < 4; ++mi)
    for (int ni = 0; ni < 4; ++ni) {
      int col = n0 + wn + ni * 16 + lr;
      const float* bias = (col < 1024) ? bq : (col < 2048) ? bk : bv;
      float bvv = bias[col & 1023];
      int rowb = m0 + wm + mi * 16 + lg * 4;
      for (int r = 0; r < 4; ++r)
        qkv[(size_t)(rowb + r) * 3072 + col] = f2b(acc[mi][ni][r] + bvv);
    }
}

// ---------------- kernel 3: V transpose -> vt[b][h][hd][s] ----------------------
__global__ void __launch_bounds__(256) k_vt(const u16* __restrict__ qkv,
                                            u16* __restrict__ vt)
{
  __shared__ __align__(16) u16 tile[64][68];
  int blk = blockIdx.x;                 // 4*16*16 = 1024
  int st = blk & 15, h = (blk >> 4) & 15, b = blk >> 8;
  int tid = threadIdx.x;
  for (int i = 0; i < 16; ++i) {
    int idx = tid + i * 256;
    int r = idx >> 6, c = idx & 63;
    tile[r][c] = qkv[(size_t)(b * 1024 + st * 64 + r) * 3072 + 2048 + h * 64 + c];
  }
  __syncthreads();
  for (int i = 0; i < 16; ++i) {
    int idx = tid + i * 256;
    int d = idx >> 6, s = idx & 63;
    vt[((size_t)(b * 16 + h) * 64 + d) * 1024 + st * 64 + s] = tile[s][d];
  }
}

// ---------------- kernel 4: head-mix  mixed[b,g,s,t] = Wc@prev + bc -------------
__global__ void __launch_bounds__(256) k_mix(
    const float* __restrict__ prev, const float* __restrict__ Wc,
    const float* __restrict__ bc, u16* __restrict__ mixed)
{
  __shared__ float wcs[256];
  __shared__ float bcs[16];
  int bsi = blockIdx.x;                 // 4096 = b*1024+s
  int b = bsi >> 10, s = bsi & 1023;
  int tid = threadIdx.x;
  wcs[tid] = Wc[tid];
  if (tid < 16) bcs[tid] = bc[tid];
  __syncthreads();
  size_t base = (size_t)b * 16 * 1048576 + (size_t)s * 1024;
  for (int half = 0; half < 2; ++half) {
    int t = half * 512 + tid * 2;
    float2 p[16];
    for (int hh = 0; hh < 16; ++hh)
      p[hh] = *(const float2*)(prev + base + (size_t)hh * 1048576 + t);
    for (int g = 0; g < 16; ++g) {
      float ax = bcs[g], ay = bcs[g];
      for (int hh = 0; hh < 16; ++hh) {
        float wv = wcs[g * 16 + hh];
        ax += wv * p[hh].x; ay += wv * p[hh].y;
      }
      unsigned int o = (unsigned int)f2b(ax) | ((unsigned int)f2b(ay) << 16);
      *(unsigned int*)(mixed + base + (size_t)g * 1048576 + t) = o;
    }
  }
}

// ---------------- kernel 5: fused attention ------------------------------------
// block = (b, h, 16-row s-block). 4 waves split the t-range (256 t each).
__global__ void __launch_bounds__(256) k_attn(
    const u16* __restrict__ qkv, const u16* __restrict__ vt,
    const u16* __restrict__ mixed, const float* __restrict__ mask,
    float* __restrict__ out)
{
  __shared__ __align__(16) u16 sc[16][1024];        // swizzled bf16 scores
  __shared__ __align__(16) float ctxw[4][16][64];
  __shared__ float mw[4][16], lw[4][16], m1s[16], l1inv[16];

  int blk = blockIdx.x;                 // 4096 = ((b*16+h)*64 + sb)
  int sb = blk & 63, bh = blk >> 6;
  int h = bh & 15, b = bh >> 4;
  int s0 = sb * 16;
  int tid = threadIdx.x;
  int l = tid & 63, w = tid >> 6;
  int lr = l & 15, lg = l >> 4;

  // Q fragments (A operand), reused across all t
  const size_t qrow = (size_t)(b * 1024 + s0 + lr) * 3072 + h * 64;
  bf16x8 aq0 = *(const bf16x8*)(qkv + qrow + lg * 8);
  bf16x8 aq1 = *(const bf16x8*)(qkv + qrow + 32 + lg * 8);

  // ---- pass A: scores = QK^T/8 + mask -> swizzled LDS (bf16) ----
  for (int tf = 0; tf < 16; ++tf) {
    int t0 = w * 256 + tf * 16;
    int trow = t0 + lr;
    const size_t krow = (size_t)(b * 1024 + trow) * 3072 + 1024 + h * 64;
    bf16x8 bk0 = *(const bf16x8*)(qkv + krow + lg * 8);
    bf16x8 bk1 = *(const bf16x8*)(qkv + krow + 32 + lg * 8);
    f32x4 acc = {0.f, 0.f, 0.f, 0.f};
    acc = MFMA16(aq0, bk0, acc);
    acc = MFMA16(aq1, bk1, acc);
    float mk = mask[b * 1024 + trow];
    for (int r = 0; r < 4; ++r) {
      int row = lg * 4 + r;
      float sv = acc[r] * 0.125f + mk;
      int addr = (((trow >> 3) ^ (row & 7)) << 3) + (trow & 7);
      sc[row][addr] = f2b(sv);
    }
  }
  __syncthreads();

  // ---- softmax-1 stats: m1, 1/l1 per row ----
  {
    int row = tid >> 4, ch = tid & 15;
    float mx = -1e30f;
    for (int c8 = 0; c8 < 8; ++c8) {
      int chunk = ch * 8 + c8;
      bf16x8 v = *(const bf16x8*)(&sc[row][(chunk ^ (row & 7)) << 3]);
      for (int j = 0; j < 8; ++j) mx = fmaxf(mx, b2f((u16)v[j]));
    }
    for (int d = 8; d >= 1; d >>= 1) mx = fmaxf(mx, __shfl_xor(mx, d));
    float sm = 0.f;
    for (int c8 = 0; c8 < 8; ++c8) {
      int chunk = ch * 8 + c8;
      bf16x8 v = *(const bf16x8*)(&sc[row][(chunk ^ (row & 7)) << 3]);
      for (int j = 0; j < 8; ++j) sm += __expf(b2f((u16)v[j]) - mx);
    }
    for (int d = 8; d >= 1; d >>= 1) sm += __shfl_xor(sm, d);
    if (ch == 0) { m1s[row] = mx; l1inv[row] = 1.0f / sm; }
  }
  __syncthreads();

  // ---- pass B: blend + online softmax-2 + PV ----
  float m1r = m1s[lr], l1r = l1inv[lr];
  float m2 = -1e30f, l2 = 0.f;
  f32x4 cacc[4] = {};
  const size_t mixrow = ((size_t)(b * 16 + h) * 1024 + s0 + lr) * 1024;
  const size_t vbase = (size_t)(b * 16 + h) * 64 * 1024;
  for (int tt = 0; tt < 8; ++tt) {
    int t0 = w * 256 + tt * 32;
    int tb = t0 + lg * 8;
    bf16x8 s8 = *(const bf16x8*)(&sc[lr][(((tb >> 3)) ^ (lr & 7)) << 3]);
    i32x4 mx4 = *(const i32x4*)(mixed + mixrow + tb);
    const u16* mxp = (const u16*)&mx4;
    float bl[8];
    float tm = -1e30f;
    for (int j = 0; j < 8; ++j) {
      float p1 = __expf(b2f((u16)s8[j]) - m1r) * l1r;
      bl[j] = 0.5f * b2f(mxp[j]) + 0.5f * p1;
      tm = fmaxf(tm, bl[j]);
    }
    tm = fmaxf(tm, __shfl_xor(tm, 16));
    tm = fmaxf(tm, __shfl_xor(tm, 32));
    float mnew = fmaxf(m2, tm);
    float scl = __expf(m2 - mnew);
    float ps = 0.f;
    bf16x8 pa;
    for (int j = 0; j < 8; ++j) {
      float p = __expf(bl[j] - mnew);
      ps += p;
      pa[j] = (short)f2b(p);
    }
    ps += __shfl_xor(ps, 16);
    ps += __shfl_xor(ps, 32);
    l2 = l2 * scl + ps;
    m2 = mnew;
    float sr[4];
    for (int r = 0; r < 4; ++r) sr[r] = __shfl(scl, lg * 4 + r);
    for (int df = 0; df < 4; ++df)
      for (int r = 0; r < 4; ++r) cacc[df][r] *= sr[r];
    for (int df = 0; df < 4; ++df) {
      bf16x8 vb = *(const bf16x8*)(vt + vbase + (size_t)(df * 16 + lr) * 1024 + tb);
      cacc[df] = MFMA16(pa, vb, cacc[df]);
    }
  }
  if (lg == 0) { mw[w][lr] = m2; lw[w][lr] = l2; }
  for (int df = 0; df < 4; ++df)
    for (int r = 0; r < 4; ++r)
      ctxw[w][lg * 4 + r][df * 16 + lr] = cacc[df][r];
  __syncthreads();

  // ---- merge 4 wave partials + final normalize + store ----
  {
    int row = tid >> 4, d4 = (tid & 15) * 4;
    float mf = fmaxf(fmaxf(mw[0][row], mw[1][row]), fmaxf(mw[2][row], mw[3][row]));
    float e[4]; float den = 0.f;
    for (int wv = 0; wv < 4; ++wv) {
      e[wv] = __expf(mw[wv][row] - mf);
      den += lw[wv][row] * e[wv];
    }
    float inv = 1.0f / den;
    f32x4 o;
    for (int dd = 0; dd < 4; ++dd) {
      float a = 0.f;
      for (int wv = 0; wv < 4; ++wv) a += ctxw[wv][row][d4 + dd] * e[wv];
      o[dd] = a * inv;
    }
    *(f32x4*)(out + ((size_t)(b * 1024 + s0 + row)) * 1024 + h * 64 + d4) = o;
  }
}

// ---------------- launcher ------------------------------------------------------
extern "C" void kernel_launch(void* const* d_in, const int* in_sizes, int n_in,
                              void* d_out, int out_size, void* d_ws, size_t ws_size,
                              hipStream_t stream) {
  const float* hidden = (const float*)d_in[0];
  const float* mask   = (const float*)d_in[1];
  const float* prev   = (const float*)d_in[2];
  const float* Wq     = (const float*)d_in[3];
  const float* bq     = (const float*)d_in[4];
  const float* Wk     = (const float*)d_in[5];
  const float* bk     = (const float*)d_in[6];
  const float* Wv     = (const float*)d_in[7];
  const float* bv     = (const float*)d_in[8];
  const float* Wc     = (const float*)d_in[9];
  const float* bc     = (const float*)d_in[10];
  float* out = (float*)d_out;
  char* ws = (char*)d_ws;

  u16* hbf   = (u16*)(ws + OFF_HBF);
  u16* wbf   = (u16*)(ws + OFF_WBF);
  u16* qkv   = (u16*)(ws + OFF_QKV);
  u16* vt    = (u16*)(ws + OFF_VT);
  u16* mixed = (u16*)(ws + OFF_MIX);

  k_convert<<<7168, 256, 0, stream>>>(hidden, Wq, Wk, Wv, hbf, wbf);
  k_qkv<<<dim3(24, 32), 256, 0, stream>>>(hbf, wbf, bq, bk, bv, qkv);
  k_vt<<<1024, 256, 0, stream>>>(qkv, vt);
  k_mix<<<4096, 256, 0, stream>>>(prev, Wc, bc, mixed);
  k_attn<<<4096, 256, 0, stream>>>(qkv, vt, mixed, mask, out);
}

// Round 2
// 598.472 us; speedup vs baseline: 1.0745x; 1.0745x over previous
//
#include <hip/hip_runtime.h>
#include <hip/hip_bf16.h>

typedef unsigned short u16;
typedef __attribute__((ext_vector_type(8))) short  bf16x8;
typedef __attribute__((ext_vector_type(4))) float  f32x4;
typedef __attribute__((ext_vector_type(4))) int    i32x4;
typedef __attribute__((ext_vector_type(4))) float  f32x4v;

#define MFMA16(a,b,c) __builtin_amdgcn_mfma_f32_16x16x32_bf16((a),(b),(c),0,0,0)

// B=4, S=1024, D=1024, H=16, HD=64
// qkv layout: [4096 rows][3072 cols] bf16 (q|k|v)
// vt layout:  [b][h][hd(64)][s(1024)] bf16
// mixed:      [b][g][s][t] bf16, stores 0.5*(Wc@prev + bc)  (ALPHA folded in)

static constexpr size_t OFF_HBF = 0;                 // 4096*1024*2
static constexpr size_t OFF_WBF = 8388608;           // 3072*1024*2
static constexpr size_t OFF_QKV = 14680064;          // 4096*3072*2
static constexpr size_t OFF_VT  = 39845888;          // 4*16*64*1024*2
static constexpr size_t OFF_MIX = 48234496;          // 4*16*1024*1024*2

__device__ __forceinline__ u16 f2b(float f) {
  unsigned int u = __builtin_bit_cast(unsigned int, f);
  unsigned int r = (u + 0x7fffu + ((u >> 16) & 1u)) >> 16;
  return (u16)r;
}
__device__ __forceinline__ float b2f(u16 x) {
  union { unsigned int u; float f; } c; c.u = ((unsigned int)x) << 16; return c.f;
}

__device__ __forceinline__ void gload_lds16(const u16* g, u16* l) {
  __builtin_amdgcn_global_load_lds(
      (const __attribute__((address_space(1))) unsigned int*)g,
      (__attribute__((address_space(3))) unsigned int*)l, 16, 0, 0);
}

// ---------------- kernel 1: fp32 -> bf16 convert -------------------------------
__global__ void __launch_bounds__(256) k_convert(
    const float* __restrict__ hid, const float* __restrict__ wq,
    const float* __restrict__ wk,  const float* __restrict__ wv,
    u16* __restrict__ hbf, u16* __restrict__ wbf)
{
  int i4 = blockIdx.x * 256 + threadIdx.x;
  f32x4v v; u16* dst;
  if (i4 < 1048576) {
    v = *(const f32x4v*)(hid + (size_t)i4 * 4);
    dst = hbf + (size_t)i4 * 4;
  } else {
    int j = (i4 - 1048576) * 4;
    const float* s = (j < 1048576) ? (wq + j)
                   : (j < 2097152) ? (wk + (j - 1048576))
                                   : (wv + (j - 2097152));
    v = *(const f32x4v*)s;
    dst = wbf + j;
  }
  u16 o[4];
  for (int k = 0; k < 4; ++k) o[k] = f2b(v[k]);
  *(unsigned long long*)dst = *(unsigned long long*)o;
}

// ---------------- kernel 2: fused QKV GEMM (global_load_lds dbuf) ---------------
// out[m][n] = sum_k A[m][k]*W[n][k] + bias[n], M=4096,N=3072,K=1024
__global__ void __launch_bounds__(256) k_qkv(
    const u16* __restrict__ Abf, const u16* __restrict__ Wbf,
    const float* __restrict__ bq, const float* __restrict__ bk,
    const float* __restrict__ bv, u16* __restrict__ qkv)
{
  __shared__ __align__(16) u16 As[2][128][32];
  __shared__ __align__(16) u16 Bs[2][128][32];
  const int n0 = blockIdx.x * 128;
  const int m0 = blockIdx.y * 128;
  const int tid = threadIdx.x;
  const int l = tid & 63, w = tid >> 6;
  const int lr = l & 15, lg = l >> 4;
  const int wm = (w >> 1) * 64, wn = (w & 1) * 64;
  // swizzled fragment column (same for all mi since tile rows are %16 aligned)
  const int sx = (lg ^ ((lr >> 1) & 3)) * 8;

  f32x4 acc[4][4] = {};

  // stage one K-slab (128x32) of A and B into buf via global_load_lds w16.
  // LDS dest is linear (chunk c*16B); global source column is XOR-swizzled so
  // that the ds_read side can read chunk (lg ^ ((row>>1)&3)) conflict-free.
  auto issue = [&](int buf, int k0) {
#pragma unroll
    for (int i = 0; i < 2; ++i) {
      int c = tid + i * 256;
      int row = c >> 2, cc = c & 3;
      int gc = cc ^ ((row >> 1) & 3);
      gload_lds16(Abf + (size_t)(m0 + row) * 1024 + k0 + gc * 8, &As[buf][row][cc * 8]);
      gload_lds16(Wbf + (size_t)(n0 + row) * 1024 + k0 + gc * 8, &Bs[buf][row][cc * 8]);
    }
  };

  issue(0, 0);
  for (int k0 = 0; k0 < 1024; k0 += 32) {
    int kb = (k0 >> 5) & 1;
    __syncthreads();                       // drains vmcnt -> buf[kb] ready
    if (k0 + 32 < 1024) issue(kb ^ 1, k0 + 32);
    bf16x8 a[4], bb[4];
#pragma unroll
    for (int mi = 0; mi < 4; ++mi)
      a[mi] = *(const bf16x8*)(&As[kb][wm + mi * 16 + lr][sx]);
#pragma unroll
    for (int ni = 0; ni < 4; ++ni)
      bb[ni] = *(const bf16x8*)(&Bs[kb][wn + ni * 16 + lr][sx]);
#pragma unroll
    for (int mi = 0; mi < 4; ++mi)
#pragma unroll
      for (int ni = 0; ni < 4; ++ni)
        acc[mi][ni] = MFMA16(a[mi], bb[ni], acc[mi][ni]);
  }
#pragma unroll
  for (int mi = 0; mi < 4; ++mi)
#pragma unroll
    for (int ni = 0; ni < 4; ++ni) {
      int col = n0 + wn + ni * 16 + lr;
      const float* bias = (col < 1024) ? bq : (col < 2048) ? bk : bv;
      float bvv = bias[col & 1023];
      int rowb = m0 + wm + mi * 16 + lg * 4;
#pragma unroll
      for (int r = 0; r < 4; ++r)
        qkv[(size_t)(rowb + r) * 3072 + col] = f2b(acc[mi][ni][r] + bvv);
    }
}

// ---------------- kernel 3: V transpose -> vt[b][h][hd][s] ----------------------
__global__ void __launch_bounds__(256) k_vt(const u16* __restrict__ qkv,
                                            u16* __restrict__ vt)
{
  __shared__ __align__(16) u16 tile[64][68];
  int blk = blockIdx.x;                 // 1024
  int st = blk & 15, h = (blk >> 4) & 15, b = blk >> 8;
  int tid = threadIdx.x;
  for (int i = 0; i < 16; ++i) {
    int idx = tid + i * 256;
    int r = idx >> 6, c = idx & 63;
    tile[r][c] = qkv[(size_t)(b * 1024 + st * 64 + r) * 3072 + 2048 + h * 64 + c];
  }
  __syncthreads();
  for (int i = 0; i < 16; ++i) {
    int idx = tid + i * 256;
    int d = idx >> 6, s = idx & 63;
    vt[((size_t)(b * 16 + h) * 64 + d) * 1024 + st * 64 + s] = tile[s][d];
  }
}

// ---------------- kernel 4: head-mix, stores 0.5*(Wc@prev+bc) as bf16 -----------
__global__ void __launch_bounds__(256) k_mix(
    const float* __restrict__ prev, const float* __restrict__ Wc,
    const float* __restrict__ bc, u16* __restrict__ mixed)
{
  __shared__ float wcs[256];
  __shared__ float bcs[16];
  int bsi = blockIdx.x;                 // 4096 = b*1024+s
  int b = bsi >> 10, s = bsi & 1023;
  int tid = threadIdx.x;
  wcs[tid] = 0.5f * Wc[tid];
  if (tid < 16) bcs[tid] = 0.5f * bc[tid];
  __syncthreads();
  size_t base = (size_t)b * 16777216 + (size_t)s * 1024;
  int t = tid * 4;
  f32x4v p[16];
#pragma unroll
  for (int hh = 0; hh < 16; ++hh)
    p[hh] = *(const f32x4v*)(prev + base + (size_t)hh * 1048576 + t);
#pragma unroll
  for (int g = 0; g < 16; ++g) {
    float bg = bcs[g];
    f32x4v a = {bg, bg, bg, bg};
#pragma unroll
    for (int hh = 0; hh < 16; ++hh)
      a += p[hh] * wcs[g * 16 + hh];
    u16 o[4];
#pragma unroll
    for (int j = 0; j < 4; ++j) o[j] = f2b(a[j]);
    *(unsigned long long*)(mixed + base + (size_t)g * 1048576 + t) =
        *(unsigned long long*)o;
  }
}

// ---------------- kernel 5: fused attention (no-max softmax) --------------------
// block = (b, h, 16-row s-block); 4 waves split the t-range (256 t each).
__global__ void __launch_bounds__(256) k_attn(
    const u16* __restrict__ qkv, const u16* __restrict__ vt,
    const u16* __restrict__ mixed, const float* __restrict__ mask,
    float* __restrict__ out)
{
  __shared__ __align__(16) char smraw[32768];       // sc (32K) then ctxw (16K)
  u16   (*sc)[1024]   = (u16 (*)[1024])smraw;
  float (*ctxw)[16][64] = (float (*)[16][64])smraw;
  __shared__ float lw[4][16], l1inv[16];

  int blk = blockIdx.x;                 // 4096 = ((b*16+h)*64 + sb)
  int sb = blk & 63, bh = blk >> 6;
  int h = bh & 15, b = bh >> 4;
  int s0 = sb * 16;
  int tid = threadIdx.x;
  int l = tid & 63, w = tid >> 6;
  int lr = l & 15, lg = l >> 4;

  const size_t qrow = (size_t)(b * 1024 + s0 + lr) * 3072 + h * 64;
  bf16x8 aq0 = *(const bf16x8*)(qkv + qrow + lg * 8);
  bf16x8 aq1 = *(const bf16x8*)(qkv + qrow + 32 + lg * 8);

  // ---- pass A: scores = QK^T/8 + mask -> swizzled bf16 LDS ----
#pragma unroll
  for (int tf = 0; tf < 16; ++tf) {
    int trow = w * 256 + tf * 16 + lr;
    const size_t krow = (size_t)(b * 1024 + trow) * 3072 + 1024 + h * 64;
    bf16x8 bk0 = *(const bf16x8*)(qkv + krow + lg * 8);
    bf16x8 bk1 = *(const bf16x8*)(qkv + krow + 32 + lg * 8);
    f32x4 acc = {0.f, 0.f, 0.f, 0.f};
    acc = MFMA16(aq0, bk0, acc);
    acc = MFMA16(aq1, bk1, acc);
    float mk = mask[b * 1024 + trow];
#pragma unroll
    for (int r = 0; r < 4; ++r) {
      int row = lg * 4 + r;
      float sv = acc[r] * 0.125f + mk;
      int addr = (((trow >> 3) ^ (row & 7)) << 3) + (trow & 7);
      sc[row][addr] = f2b(sv);
    }
  }
  __syncthreads();

  // ---- softmax-1 denominator (no max needed: logits bounded) ----
  {
    int row = tid >> 4, ch = tid & 15;
    float sm = 0.f;
#pragma unroll
    for (int c8 = 0; c8 < 8; ++c8) {
      int chunk = ch * 8 + c8;
      bf16x8 v = *(const bf16x8*)(&sc[row][(chunk ^ (row & 7)) << 3]);
#pragma unroll
      for (int j = 0; j < 8; ++j) sm += __expf(b2f((u16)v[j]));
    }
    for (int d = 8; d >= 1; d >>= 1) sm += __shfl_xor(sm, d);
    if (ch == 0) l1inv[row] = 1.0f / sm;
  }
  __syncthreads();

  // ---- pass B: blend + unnormalized exp + PV (no online rescale) ----
  float l1h = 0.5f * l1inv[lr];     // folds the 0.5 blend weight
  float l2 = 0.f;
  f32x4 cacc[4] = {};
  const size_t mixrow = ((size_t)(b * 16 + h) * 1024 + s0 + lr) * 1024;
  const size_t vbase = (size_t)(b * 16 + h) * 64 * 1024;
  i32x4 mx_next = *(const i32x4*)(mixed + mixrow + w * 256 + lg * 8);
#pragma unroll
  for (int tt = 0; tt < 8; ++tt) {
    int tb = w * 256 + tt * 32 + lg * 8;
    i32x4 mx4 = mx_next;
    if (tt < 7) mx_next = *(const i32x4*)(mixed + mixrow + tb + 32);
    bf16x8 s8 = *(const bf16x8*)(&sc[lr][((tb >> 3) ^ (lr & 7)) << 3]);
    const u16* mxp = (const u16*)&mx4;
    bf16x8 pa;
    float ps = 0.f;
#pragma unroll
    for (int j = 0; j < 8; ++j) {
      float bl = b2f(mxp[j]) + __expf(b2f((u16)s8[j])) * l1h;  // 0.5m + 0.5p1
      float p = __expf(bl);
      ps += p;
      pa[j] = (short)f2b(p);
    }
    l2 += ps;
#pragma unroll
    for (int df = 0; df < 4; ++df) {
      bf16x8 vb = *(const bf16x8*)(vt + vbase + (size_t)(df * 16 + lr) * 1024 + tb);
      cacc[df] = MFMA16(pa, vb, cacc[df]);
    }
  }
  l2 += __shfl_xor(l2, 16);
  l2 += __shfl_xor(l2, 32);

  __syncthreads();                       // all waves done reading sc
  if (lg == 0) lw[w][lr] = l2;
#pragma unroll
  for (int df = 0; df < 4; ++df)
#pragma unroll
    for (int r = 0; r < 4; ++r)
      ctxw[w][lg * 4 + r][df * 16 + lr] = cacc[df][r];
  __syncthreads();

  // ---- merge 4 wave partials (plain sums) + normalize + store ----
  {
    int row = tid >> 4, d4 = (tid & 15) * 4;
    float den = lw[0][row] + lw[1][row] + lw[2][row] + lw[3][row];
    float inv = 1.0f / den;
    f32x4 o;
#pragma unroll
    for (int dd = 0; dd < 4; ++dd) {
      float a = ctxw[0][row][d4 + dd] + ctxw[1][row][d4 + dd] +
                ctxw[2][row][d4 + dd] + ctxw[3][row][d4 + dd];
      o[dd] = a * inv;
    }
    *(f32x4*)(out + ((size_t)(b * 1024 + s0 + row)) * 1024 + h * 64 + d4) = o;
  }
}

// ---------------- launcher ------------------------------------------------------
extern "C" void kernel_launch(void* const* d_in, const int* in_sizes, int n_in,
                              void* d_out, int out_size, void* d_ws, size_t ws_size,
                              hipStream_t stream) {
  const float* hidden = (const float*)d_in[0];
  const float* mask   = (const float*)d_in[1];
  const float* prev   = (const float*)d_in[2];
  const float* Wq     = (const float*)d_in[3];
  const float* bq     = (const float*)d_in[4];
  const float* Wk     = (const float*)d_in[5];
  const float* bk     = (const float*)d_in[6];
  const float* Wv     = (const float*)d_in[7];
  const float* bv     = (const float*)d_in[8];
  const float* Wc     = (const float*)d_in[9];
  const float* bc     = (const float*)d_in[10];
  float* out = (float*)d_out;
  char* ws = (char*)d_ws;

  u16* hbf   = (u16*)(ws + OFF_HBF);
  u16* wbf   = (u16*)(ws + OFF_WBF);
  u16* qkv   = (u16*)(ws + OFF_QKV);
  u16* vt    = (u16*)(ws + OFF_VT);
  u16* mixed = (u16*)(ws + OFF_MIX);

  k_convert<<<7168, 256, 0, stream>>>(hidden, Wq, Wk, Wv, hbf, wbf);
  k_qkv<<<dim3(24, 32), 256, 0, stream>>>(hbf, wbf, bq, bk, bv, qkv);
  k_vt<<<1024, 256, 0, stream>>>(qkv, vt);
  k_mix<<<4096, 256, 0, stream>>>(prev, Wc, bc, mixed);
  k_attn<<<4096, 256, 0, stream>>>(qkv, vt, mixed, mask, out);
}

// Round 3
// 597.685 us; speedup vs baseline: 1.0760x; 1.0013x over previous
//
#include <hip/hip_runtime.h>
#include <hip/hip_bf16.h>

typedef unsigned short u16;
typedef unsigned long long u64;
typedef __attribute__((ext_vector_type(8))) short  bf16x8;
typedef __attribute__((ext_vector_type(4))) float  f32x4;
typedef __attribute__((ext_vector_type(4))) int    i32x4;
typedef __attribute__((ext_vector_type(4))) float  f32x4v;

#define MFMA16(a,b,c) __builtin_amdgcn_mfma_f32_16x16x32_bf16((a),(b),(c),0,0,0)
#define EXP2(x) __builtin_amdgcn_exp2f(x)

// B=4, S=1024, D=1024, H=16, HD=64
// qkv layout: [4096 rows][2048 cols] bf16 (q|k); V goes straight to vt
// vt layout:  [b][h][hd(64)][s(1024)] bf16
// mixed:      [b][g][s][t] bf16, stores 0.5*log2e*(Wc@prev + bc)
// scores LDS: stored pre-scaled by log2e -> all exps are raw v_exp_f32

static constexpr size_t OFF_HBF = 0;                  // 4096*1024*2 = 8388608
static constexpr size_t OFF_WBF = 8388608;            // 3072*1024*2 = 6291456
static constexpr size_t OFF_QKV = 14680064;           // 4096*2048*2 = 16777216
static constexpr size_t OFF_VT  = 31457280;           // 4*16*64*1024*2 = 8388608
static constexpr size_t OFF_MIX = 39845888;           // 4*16*1024*1024*2 = 134217728

static constexpr float LOG2E  = 1.44269504088896340736f;
static constexpr float SSCALE = 0.125f * LOG2E;       // QK^T scale * log2e
static constexpr float HALF2E = 0.5f * LOG2E;         // blend weight * log2e

__device__ __forceinline__ u16 f2b(float f) {
  unsigned int u = __builtin_bit_cast(unsigned int, f);
  unsigned int r = (u + 0x7fffu + ((u >> 16) & 1u)) >> 16;
  return (u16)r;
}
__device__ __forceinline__ float b2f(u16 x) {
  union { unsigned int u; float f; } c; c.u = ((unsigned int)x) << 16; return c.f;
}

__device__ __forceinline__ void gload_lds16(const u16* g, u16* l) {
  __builtin_amdgcn_global_load_lds(
      (const __attribute__((address_space(1))) unsigned int*)g,
      (__attribute__((address_space(3))) unsigned int*)l, 16, 0, 0);
}

// ---------------- kernel 1: fp32 -> bf16 convert -------------------------------
__global__ void __launch_bounds__(256) k_convert(
    const float* __restrict__ hid, const float* __restrict__ wq,
    const float* __restrict__ wk,  const float* __restrict__ wv,
    u16* __restrict__ hbf, u16* __restrict__ wbf)
{
  int i4 = blockIdx.x * 256 + threadIdx.x;
  f32x4v v; u16* dst;
  if (i4 < 1048576) {
    v = *(const f32x4v*)(hid + (size_t)i4 * 4);
    dst = hbf + (size_t)i4 * 4;
  } else {
    int j = (i4 - 1048576) * 4;
    const float* s = (j < 1048576) ? (wq + j)
                   : (j < 2097152) ? (wk + (j - 1048576))
                                   : (wv + (j - 2097152));
    v = *(const f32x4v*)s;
    dst = wbf + j;
  }
  u16 o[4];
  for (int k = 0; k < 4; ++k) o[k] = f2b(v[k]);
  *(u64*)dst = *(u64*)o;
}

// ---------------- kernel 2: fused QKV GEMM; V written transposed ---------------
// M=4096, N=3072, K=1024. cols<2048 -> qkv[m][col]; cols>=2048 -> vt transposed.
__global__ void __launch_bounds__(256) k_qkv(
    const u16* __restrict__ Abf, const u16* __restrict__ Wbf,
    const float* __restrict__ bq, const float* __restrict__ bk,
    const float* __restrict__ bv, u16* __restrict__ qkv, u16* __restrict__ vt)
{
  __shared__ __align__(16) u16 As[2][128][32];
  __shared__ __align__(16) u16 Bs[2][128][32];
  const int n0 = blockIdx.x * 128;
  const int m0 = blockIdx.y * 128;
  const int tid = threadIdx.x;
  const int l = tid & 63, w = tid >> 6;
  const int lr = l & 15, lg = l >> 4;
  const int wm = (w >> 1) * 64, wn = (w & 1) * 64;
  const int sx = (lg ^ ((lr >> 1) & 3)) * 8;

  f32x4 acc[4][4] = {};

  auto issue = [&](int buf, int k0) {
#pragma unroll
    for (int i = 0; i < 2; ++i) {
      int c = tid + i * 256;
      int row = c >> 2, cc = c & 3;
      int gc = cc ^ ((row >> 1) & 3);
      gload_lds16(Abf + (size_t)(m0 + row) * 1024 + k0 + gc * 8, &As[buf][row][cc * 8]);
      gload_lds16(Wbf + (size_t)(n0 + row) * 1024 + k0 + gc * 8, &Bs[buf][row][cc * 8]);
    }
  };

  issue(0, 0);
  for (int k0 = 0; k0 < 1024; k0 += 32) {
    int kb = (k0 >> 5) & 1;
    __syncthreads();
    if (k0 + 32 < 1024) issue(kb ^ 1, k0 + 32);
    bf16x8 a[4], bb[4];
#pragma unroll
    for (int mi = 0; mi < 4; ++mi)
      a[mi] = *(const bf16x8*)(&As[kb][wm + mi * 16 + lr][sx]);
#pragma unroll
    for (int ni = 0; ni < 4; ++ni)
      bb[ni] = *(const bf16x8*)(&Bs[kb][wn + ni * 16 + lr][sx]);
#pragma unroll
    for (int mi = 0; mi < 4; ++mi)
#pragma unroll
      for (int ni = 0; ni < 4; ++ni)
        acc[mi][ni] = MFMA16(a[mi], bb[ni], acc[mi][ni]);
  }
#pragma unroll
  for (int mi = 0; mi < 4; ++mi)
#pragma unroll
    for (int ni = 0; ni < 4; ++ni) {
      int col = n0 + wn + ni * 16 + lr;
      const float* bias = (col < 1024) ? bq : (col < 2048) ? bk : bv;
      float bvv = bias[col & 1023];
      int rowb = m0 + wm + mi * 16 + lg * 4;
      if (col < 2048) {
#pragma unroll
        for (int r = 0; r < 4; ++r)
          qkv[(size_t)(rowb + r) * 2048 + col] = f2b(acc[mi][ni][r] + bvv);
      } else {
        int hh = (col >> 6) & 15, d = col & 63;
        int bb2 = rowb >> 10, sl = rowb & 1023;
        u16 o[4];
#pragma unroll
        for (int r = 0; r < 4; ++r) o[r] = f2b(acc[mi][ni][r] + bvv);
        *(u64*)(vt + ((size_t)(bb2 * 16 + hh) * 64 + d) * 1024 + sl) = *(u64*)o;
      }
    }
}

// ---------------- kernel 3: head-mix, stores 0.5*log2e*(Wc@prev+bc) ------------
__global__ void __launch_bounds__(256) k_mix(
    const float* __restrict__ prev, const float* __restrict__ Wc,
    const float* __restrict__ bc, u16* __restrict__ mixed)
{
  __shared__ float wcs[256];
  __shared__ float bcs[16];
  int bsi = blockIdx.x;                 // 4096 = b*1024+s
  int b = bsi >> 10, s = bsi & 1023;
  int tid = threadIdx.x;
  wcs[tid] = HALF2E * Wc[tid];
  if (tid < 16) bcs[tid] = HALF2E * bc[tid];
  __syncthreads();
  size_t base = (size_t)b * 16777216 + (size_t)s * 1024;
  int t = tid * 4;
  f32x4v p[16];
#pragma unroll
  for (int hh = 0; hh < 16; ++hh)
    p[hh] = *(const f32x4v*)(prev + base + (size_t)hh * 1048576 + t);
#pragma unroll
  for (int g = 0; g < 16; ++g) {
    float bg = bcs[g];
    f32x4v a = {bg, bg, bg, bg};
#pragma unroll
    for (int hh = 0; hh < 16; ++hh)
      a += p[hh] * wcs[g * 16 + hh];
    u16 o[4];
#pragma unroll
    for (int j = 0; j < 4; ++j) o[j] = f2b(a[j]);
    *(u64*)(mixed + base + (size_t)g * 1048576 + t) = *(u64*)o;
  }
}

// ---------------- kernel 4: fused attention ------------------------------------
// block = (b, h, 16-row s-block); 4 waves split t (256 each). All exps are exp2.
__global__ void __launch_bounds__(256) k_attn(
    const u16* __restrict__ qkv, const u16* __restrict__ vt,
    const u16* __restrict__ mixed, const float* __restrict__ mask,
    float* __restrict__ out)
{
  __shared__ __align__(16) char smraw[32768];       // sc (32K) | ctxw (16K)
  u16   (*sc)[1024]   = (u16 (*)[1024])smraw;
  float (*ctxw)[16][64] = (float (*)[16][64])smraw;
  __shared__ float lw[4][16], l1inv[16];

  int blk = blockIdx.x;                 // 4096 = ((b*16+h)*64 + sb)
  int sb = blk & 63, bh = blk >> 6;
  int h = bh & 15, b = bh >> 4;
  int s0 = sb * 16;
  int tid = threadIdx.x;
  int l = tid & 63, w = tid >> 6;
  int lr = l & 15, lg = l >> 4;

  const size_t qrow = (size_t)(b * 1024 + s0 + lr) * 2048 + h * 64;
  bf16x8 aq0 = *(const bf16x8*)(qkv + qrow + lg * 8);
  bf16x8 aq1 = *(const bf16x8*)(qkv + qrow + 32 + lg * 8);

  // ---- pass A: sc = log2e*(QK^T/8 + mask) -> swizzled bf16 LDS ----
#pragma unroll
  for (int tf = 0; tf < 16; ++tf) {
    int trow = w * 256 + tf * 16 + lr;
    const size_t krow = (size_t)(b * 1024 + trow) * 2048 + 1024 + h * 64;
    bf16x8 bk0 = *(const bf16x8*)(qkv + krow + lg * 8);
    bf16x8 bk1 = *(const bf16x8*)(qkv + krow + 32 + lg * 8);
    f32x4 acc = {0.f, 0.f, 0.f, 0.f};
    acc = MFMA16(aq0, bk0, acc);
    acc = MFMA16(aq1, bk1, acc);
    float mk = mask[b * 1024 + trow] * LOG2E;
#pragma unroll
    for (int r = 0; r < 4; ++r) {
      int row = lg * 4 + r;
      float sv = acc[r] * SSCALE + mk;
      int addr = (((trow >> 3) ^ (row & 7)) << 3) + (trow & 7);
      sc[row][addr] = f2b(sv);
    }
  }
  __syncthreads();

  // ---- softmax-1 denominator ----
  {
    int row = tid >> 4, ch = tid & 15;
    float sm = 0.f;
#pragma unroll
    for (int c8 = 0; c8 < 8; ++c8) {
      int chunk = ch * 8 + c8;
      bf16x8 v = *(const bf16x8*)(&sc[row][(chunk ^ (row & 7)) << 3]);
#pragma unroll
      for (int j = 0; j < 8; ++j) sm += EXP2(b2f((u16)v[j]));
    }
    for (int d = 8; d >= 1; d >>= 1) sm += __shfl_xor(sm, d);
    if (ch == 0) l1inv[row] = 1.0f / sm;
  }
  __syncthreads();

  // ---- pass B: blend + unnormalized exp2 + PV ----
  float l1h = HALF2E * l1inv[lr];
  float l2 = 0.f;
  f32x4 cacc[4] = {};
  const size_t mixrow = ((size_t)(b * 16 + h) * 1024 + s0 + lr) * 1024;
  const size_t vbase = (size_t)(b * 16 + h) * 64 * 1024;
  // prefetch the full mixed row-slice (8 x 16B) up front to hide HBM latency
  i32x4 mxa[8];
#pragma unroll
  for (int tt = 0; tt < 8; ++tt)
    mxa[tt] = *(const i32x4*)(mixed + mixrow + w * 256 + tt * 32 + lg * 8);
#pragma unroll
  for (int tt = 0; tt < 8; ++tt) {
    int tb = w * 256 + tt * 32 + lg * 8;
    bf16x8 s8 = *(const bf16x8*)(&sc[lr][((tb >> 3) ^ (lr & 7)) << 3]);
    const u16* mxp = (const u16*)&mxa[tt];
    bf16x8 pa;
    float ps = 0.f;
#pragma unroll
    for (int j = 0; j < 8; ++j) {
      float bl = b2f(mxp[j]) + EXP2(b2f((u16)s8[j])) * l1h;  // log2e*(.5m+.5p1)
      float p = EXP2(bl);
      ps += p;
      pa[j] = (short)f2b(p);
    }
    l2 += ps;
#pragma unroll
    for (int df = 0; df < 4; ++df) {
      bf16x8 vb = *(const bf16x8*)(vt + vbase + (size_t)(df * 16 + lr) * 1024 + tb);
      cacc[df] = MFMA16(pa, vb, cacc[df]);
    }
  }
  l2 += __shfl_xor(l2, 16);
  l2 += __shfl_xor(l2, 32);

  __syncthreads();                       // all waves done reading sc
  if (lg == 0) lw[w][lr] = l2;
#pragma unroll
  for (int df = 0; df < 4; ++df)
#pragma unroll
    for (int r = 0; r < 4; ++r)
      ctxw[w][lg * 4 + r][df * 16 + lr] = cacc[df][r];
  __syncthreads();

  // ---- merge 4 wave partials + normalize + store ----
  {
    int row = tid >> 4, d4 = (tid & 15) * 4;
    float den = lw[0][row] + lw[1][row] + lw[2][row] + lw[3][row];
    float inv = 1.0f / den;
    f32x4 o;
#pragma unroll
    for (int dd = 0; dd < 4; ++dd) {
      float a = ctxw[0][row][d4 + dd] + ctxw[1][row][d4 + dd] +
                ctxw[2][row][d4 + dd] + ctxw[3][row][d4 + dd];
      o[dd] = a * inv;
    }
    *(f32x4*)(out + ((size_t)(b * 1024 + s0 + row)) * 1024 + h * 64 + d4) = o;
  }
}

// ---------------- launcher ------------------------------------------------------
extern "C" void kernel_launch(void* const* d_in, const int* in_sizes, int n_in,
                              void* d_out, int out_size, void* d_ws, size_t ws_size,
                              hipStream_t stream) {
  const float* hidden = (const float*)d_in[0];
  const float* mask   = (const float*)d_in[1];
  const float* prev   = (const float*)d_in[2];
  const float* Wq     = (const float*)d_in[3];
  const float* bq     = (const float*)d_in[4];
  const float* Wk     = (const float*)d_in[5];
  const float* bk     = (const float*)d_in[6];
  const float* Wv     = (const float*)d_in[7];
  const float* bv     = (const float*)d_in[8];
  const float* Wc     = (const float*)d_in[9];
  const float* bc     = (const float*)d_in[10];
  float* out = (float*)d_out;
  char* ws = (char*)d_ws;

  u16* hbf   = (u16*)(ws + OFF_HBF);
  u16* wbf   = (u16*)(ws + OFF_WBF);
  u16* qkv   = (u16*)(ws + OFF_QKV);
  u16* vt    = (u16*)(ws + OFF_VT);
  u16* mixed = (u16*)(ws + OFF_MIX);

  k_convert<<<7168, 256, 0, stream>>>(hidden, Wq, Wk, Wv, hbf, wbf);
  k_qkv<<<dim3(24, 32), 256, 0, stream>>>(hbf, wbf, bq, bk, bv, qkv, vt);
  k_mix<<<4096, 256, 0, stream>>>(prev, Wc, bc, mixed);
  k_attn<<<4096, 256, 0, stream>>>(qkv, vt, mixed, mask, out);
}